// Round 5
// baseline (627.191 us; speedup 1.0000x reference)
//
#include <hip/hip_runtime.h>
#include <hip/hip_bf16.h>
#include <stdint.h>

// Problem constants
#define T_TOK 4096   // B*S
#define H_DIM 1024
#define F_DIM 2816
#define E_NUM 8
#define ROWS_CAP 9216   // 8192 + 8*128 padding headroom
#define TOTAL_MT 72     // ROWS_CAP / 128

typedef float  f32x4  __attribute__((ext_vector_type(4)));
typedef __bf16 bf16x8 __attribute__((ext_vector_type(8)));
typedef unsigned short ushort8_t __attribute__((ext_vector_type(8)));

__device__ __forceinline__ unsigned short f32_bf16(float f) {
  union { float f; unsigned u; } v; v.f = f;
  unsigned r = v.u + 0x7fffu + ((v.u >> 16) & 1u);
  return (unsigned short)(r >> 16);
}

__device__ __forceinline__ void async16(const void* g, void* l) {
  __builtin_amdgcn_global_load_lds(
      (__attribute__((address_space(1))) void*)(g),
      (__attribute__((address_space(3))) void*)(l),
      16, 0, 0);
}

__device__ __forceinline__ f32x4 mfma16(bf16x8 a, bf16x8 b, f32x4 c) {
  return __builtin_amdgcn_mfma_f32_16x16x32_bf16(a, b, c, 0, 0, 0);
}

// ---------------- converts ----------------

// x fp32 [T,H] -> bf16 [T,H]
__global__ __launch_bounds__(256) void conv_x_kernel(const float* __restrict__ x,
                                                     unsigned short* __restrict__ xb) {
  int i = blockIdx.x * 256 + threadIdx.x;   // one float4 per thread
  float4 v = ((const float4*)x)[i];
  ushort4 o;
  o.x = f32_bf16(v.x); o.y = f32_bf16(v.y); o.z = f32_bf16(v.z); o.w = f32_bf16(v.w);
  ((ushort4*)xb)[i] = o;
}

// Unified transpose+convert, flat live grid, 16B stores.
// src [R][C] fp32 -> dst [C][R] bf16, 64x64 tiles.
__global__ __launch_bounds__(256) void transpose_all(const float* __restrict__ wg,
                                                     const float* __restrict__ wu,
                                                     const float* __restrict__ wd,
                                                     unsigned short* __restrict__ Wgt,
                                                     unsigned short* __restrict__ Wut,
                                                     unsigned short* __restrict__ Wdt) {
  int bx = blockIdx.x;            // [0, 2112)
  int mz = bx / 704, local = bx % 704;
  const float* s; unsigned short* d; int R, C, tx;
  size_t mat = (size_t)H_DIM * F_DIM;
  if (mz == 0)      { s = wg; d = Wgt; R = H_DIM; C = F_DIM; tx = 44; }
  else if (mz == 1) { s = wu; d = Wut; R = H_DIM; C = F_DIM; tx = 44; }
  else              { s = wd; d = Wdt; R = F_DIM; C = H_DIM; tx = 16; }
  int e = blockIdx.y;
  s += e * mat; d += e * mat;
  int c0 = (local % tx) * 64;
  int r0 = (local / tx) * 64;

  __shared__ float tile[64 * 65];
  int tid = threadIdx.x;
  int rr = tid >> 4, c4 = tid & 15;
#pragma unroll
  for (int it = 0; it < 4; it++) {
    int r = rr + 16 * it;
    float4 v = *(const float4*)(s + (size_t)(r0 + r) * C + c0 + c4 * 4);
    tile[r * 65 + c4 * 4 + 0] = v.x;
    tile[r * 65 + c4 * 4 + 1] = v.y;
    tile[r * 65 + c4 * 4 + 2] = v.z;
    tile[r * 65 + c4 * 4 + 3] = v.w;
  }
  __syncthreads();
#pragma unroll
  for (int it = 0; it < 2; it++) {
    int c = tid + it * 256;
    int col = c >> 3, q = c & 7;
    ushort8_t o;
#pragma unroll
    for (int k = 0; k < 8; k++) o[k] = f32_bf16(tile[(q * 8 + k) * 65 + col]);
    *(ushort8_t*)(d + (size_t)(c0 + col) * R + r0 + q * 8) = o;
  }
}

// ---------------- router ----------------

__global__ __launch_bounds__(256) void router_kernel(const float* __restrict__ x,
                                                     const float* __restrict__ rw,
                                                     int* __restrict__ t2i,
                                                     float* __restrict__ t2w,
                                                     int* __restrict__ counts,
                                                     float* __restrict__ psum) {
  __shared__ float srw[E_NUM * H_DIM];  // 32 KB
  __shared__ float sP[E_NUM];
  __shared__ int sC[E_NUM];
  int tid = threadIdx.x;
  for (int i = tid; i < E_NUM * H_DIM; i += 256) srw[i] = rw[i];
  if (tid < E_NUM) { sP[tid] = 0.f; sC[tid] = 0; }
  __syncthreads();
  int w = tid >> 6, lane = tid & 63;
  for (int it = 0; it < 4; ++it) {
    int t = blockIdx.x * 16 + w * 4 + it;
    float acc[E_NUM];
#pragma unroll
    for (int e = 0; e < E_NUM; e++) acc[e] = 0.f;
    const float* xr = x + (size_t)t * H_DIM;
    for (int h = lane; h < H_DIM; h += 64) {
      float xv = xr[h];
#pragma unroll
      for (int e = 0; e < E_NUM; e++) acc[e] += xv * srw[e * H_DIM + h];
    }
#pragma unroll
    for (int e = 0; e < E_NUM; e++) {
      float v = acc[e];
      for (int o = 32; o > 0; o >>= 1) v += __shfl_down(v, o, 64);
      acc[e] = __shfl(v, 0, 64);
    }
    if (lane == 0) {
      float mx = acc[0];
#pragma unroll
      for (int e = 1; e < E_NUM; e++) mx = fmaxf(mx, acc[e]);
      float pr[E_NUM], s = 0.f;
#pragma unroll
      for (int e = 0; e < E_NUM; e++) { pr[e] = __expf(acc[e] - mx); s += pr[e]; }
      float inv = 1.f / s;
#pragma unroll
      for (int e = 0; e < E_NUM; e++) atomicAdd(&sP[e], pr[e] * inv);
      int i0 = 0; float v0 = acc[0];
#pragma unroll
      for (int e = 1; e < E_NUM; e++) if (acc[e] > v0) { v0 = acc[e]; i0 = e; }
      int i1 = -1; float v1 = -3.4e38f;
#pragma unroll
      for (int e = 0; e < E_NUM; e++) if (e != i0 && acc[e] > v1) { v1 = acc[e]; i1 = e; }
      float e1 = __expf(v1 - v0);
      float w0 = 1.f / (1.f + e1);
      t2i[2 * t] = i0; t2i[2 * t + 1] = i1;
      t2w[2 * t] = w0; t2w[2 * t + 1] = e1 * w0;
      atomicAdd(&sC[i0], 1); atomicAdd(&sC[i1], 1);
    }
  }
  __syncthreads();
  if (tid < E_NUM) { atomicAdd(&counts[tid], sC[tid]); atomicAdd(&psum[tid], sP[tid]); }
}

__global__ void scan_aux_kernel(const int* __restrict__ counts, const float* __restrict__ psum,
                                int* __restrict__ offsets, int* __restrict__ cursors,
                                float* __restrict__ aux_out) {
  if (threadIdx.x == 0 && blockIdx.x == 0) {
    int off = 0; float aux = 0.f;
    for (int e = 0; e < E_NUM; e++) {
      offsets[e] = off;
      cursors[e] = off;
      off += (counts[e] + 127) & ~127;
      aux += ((float)counts[e] / 8192.0f) * (psum[e] / 4096.0f);
    }
    offsets[E_NUM] = off;
    *aux_out = 8.0f * aux;
  }
}

__global__ __launch_bounds__(256) void assign_kernel(const int* __restrict__ t2i,
                                                     const float* __restrict__ t2w,
                                                     int* __restrict__ cursors,
                                                     int* __restrict__ row2token,
                                                     float* __restrict__ roww,
                                                     int* __restrict__ t2row) {
  int t = blockIdx.x * 256 + threadIdx.x;
#pragma unroll
  for (int s = 0; s < 2; s++) {
    int e = t2i[2 * t + s];
    int p = atomicAdd(&cursors[e], 1);
    row2token[p] = t;
    roww[p] = t2w[2 * t + s];
    t2row[2 * t + s] = p;
  }
}

// Map a global (padded) row-tile index to its expert via offsets[].
__device__ __forceinline__ int find_expert(const int* __restrict__ offsets, int row0,
                                           int& off_out) {
  int esel = -1, off = 0;
#pragma unroll
  for (int e = 0; e < E_NUM; e++) {
    int lo = offsets[e], hi = offsets[e + 1];
    if (row0 >= lo && row0 < hi) { esel = e; off = lo; }
  }
  off_out = off;
  return esel;
}

// ---------------- fused gate/up GEMM ----------------
// act[row, f] = silu(x@Wg) * (x@Wu), bf16.  BM=128, BN=64, BK=64.
// LDS chunks XOR-swizzled (slot q' = q ^ (row&7)) -> ds_read_b128 ~2-way
// bank aliasing instead of 16-way; swizzle applied to the GLOBAL offset so
// global_load_lds keeps its wave-uniform-base + lane*16 contract.
__global__ __launch_bounds__(256) void gateup_kernel(
    const unsigned short* __restrict__ xb,
    const unsigned short* __restrict__ wgt,
    const unsigned short* __restrict__ wut,
    unsigned short* __restrict__ act,
    const int* __restrict__ counts, const int* __restrict__ offsets,
    const int* __restrict__ row2token) {
  int g = blockIdx.x;
  int row0 = g * 128;
  int off;
  int e = find_expert(offsets, row0, off);
  if (e < 0) return;
  int cnt = counts[e];
  int rowbase = row0 - off;
  int ntile = blockIdx.y;     // F/64 = 44

  __shared__ __align__(16) unsigned short smA[128 * 64];  // 16 KB
  __shared__ __align__(16) unsigned short smG[64 * 64];   // 8 KB
  __shared__ __align__(16) unsigned short smU[64 * 64];   // 8 KB

  int tid = threadIdx.x;
  int w = tid >> 6, lane = tid & 63;
  int wm = w & 1, wn = w >> 1;  // wave tile 64x32 within 128x64

  // staging: A = 1024 16B-chunks (4/thread), G,U = 512 (2/thread)
  const unsigned short* gA[4]; unsigned short* lA[4];
  size_t wb = (size_t)e * F_DIM * H_DIM;
#pragma unroll
  for (int i = 0; i < 4; i++) {
    int c = tid + i * 256;
    int r = c >> 3, qs = c & 7;
    int q = qs ^ (r & 7);
    int tok = (rowbase + r < cnt) ? row2token[off + rowbase + r] : 0;
    gA[i] = xb + (size_t)tok * H_DIM + q * 8;
    lA[i] = smA + c * 8;
  }
  const unsigned short* gG[2]; const unsigned short* gU[2];
  unsigned short* lG[2]; unsigned short* lU[2];
#pragma unroll
  for (int i = 0; i < 2; i++) {
    int c = tid + i * 256;
    int r = c >> 3, qs = c & 7;
    int q = qs ^ (r & 7);
    gG[i] = wgt + wb + (size_t)(ntile * 64 + r) * H_DIM + q * 8;
    gU[i] = wut + wb + (size_t)(ntile * 64 + r) * H_DIM + q * 8;
    lG[i] = smG + c * 8;
    lU[i] = smU + c * 8;
  }

  f32x4 accg[4][2], accu[4][2];
#pragma unroll
  for (int i = 0; i < 4; i++)
#pragma unroll
    for (int j = 0; j < 2; j++) {
      accg[i][j] = (f32x4){0.f, 0.f, 0.f, 0.f};
      accu[i][j] = (f32x4){0.f, 0.f, 0.f, 0.f};
    }

  int m = lane & 15, quad = lane >> 4;
  for (int k0 = 0; k0 < H_DIM; k0 += 64) {
#pragma unroll
    for (int i = 0; i < 4; i++) async16(gA[i] + k0, lA[i]);
#pragma unroll
    for (int i = 0; i < 2; i++) {
      async16(gG[i] + k0, lG[i]);
      async16(gU[i] + k0, lU[i]);
    }
    __syncthreads();
#pragma unroll
    for (int h = 0; h < 2; h++) {
      bf16x8 a[4], bg[2], bu[2];
#pragma unroll
      for (int i = 0; i < 4; i++) {
        int row = wm * 64 + 16 * i + m;
        a[i] = *(const bf16x8*)(smA + row * 64 + (((h * 4 + quad) ^ (row & 7)) * 8));
      }
#pragma unroll
      for (int j = 0; j < 2; j++) {
        int row = wn * 32 + 16 * j + m;
        int o = row * 64 + (((h * 4 + quad) ^ (row & 7)) * 8);
        bg[j] = *(const bf16x8*)(smG + o);
        bu[j] = *(const bf16x8*)(smU + o);
      }
#pragma unroll
      for (int i = 0; i < 4; i++)
#pragma unroll
        for (int j = 0; j < 2; j++) {
          accg[i][j] = mfma16(a[i], bg[j], accg[i][j]);
          accu[i][j] = mfma16(a[i], bu[j], accu[i][j]);
        }
    }
    __syncthreads();
  }

#pragma unroll
  for (int i = 0; i < 4; i++)
#pragma unroll
    for (int j = 0; j < 2; j++)
#pragma unroll
      for (int r = 0; r < 4; r++) {
        int rt = wm * 64 + 16 * i + quad * 4 + r;
        int ct = wn * 32 + 16 * j + m;
        float g2 = accg[i][j][r], u = accu[i][j][r];
        float sv = g2 / (1.f + __expf(-g2)) * u;
        act[(size_t)(off + rowbase + rt) * F_DIM + ntile * 64 + ct] = f32_bf16(sv);
      }
}

// ---------------- down GEMM, split-k x2 -> Y scratch ----------------
// Y[ks][row, h] = w_row * (act[:, ks*1408:+1408] @ Wd[ks*1408:+1408, :]).
// BM=128, BN=128, BK=32, XOR-swizzled LDS (slot q' = q ^ (row&3)).
__global__ __launch_bounds__(256) void down_kernel(
    const unsigned short* __restrict__ act,
    const unsigned short* __restrict__ wdt,   // [E][H][F] k-contig
    const int* __restrict__ counts, const int* __restrict__ offsets,
    const float* __restrict__ roww,
    float* __restrict__ Y) {
  int g = blockIdx.x;
  int row0 = g * 128;
  int off;
  int e = find_expert(offsets, row0, off);
  if (e < 0) return;
  int cnt = counts[e];
  int rowbase = row0 - off;
  int ntile = blockIdx.y;  // H/128 = 8
  int ks = blockIdx.z;     // split-k slice
  int kbase = ks * (F_DIM / 2);

  __shared__ __align__(16) unsigned short smA[128 * 32];
  __shared__ __align__(16) unsigned short smB[128 * 32];

  int tid = threadIdx.x;
  int w = tid >> 6, lane = tid & 63;
  int wm = w & 1, wn = w >> 1;  // wave tile 64x64

  const unsigned short* gA[2]; const unsigned short* gB[2];
  unsigned short* lA[2]; unsigned short* lB[2];
  size_t wb = (size_t)e * H_DIM * F_DIM;
#pragma unroll
  for (int i = 0; i < 2; i++) {
    int c = tid + i * 256;
    int r = c >> 2, qs = c & 3;
    int q = qs ^ (r & 3);
    gA[i] = act + (size_t)(off + rowbase + r) * F_DIM + kbase + q * 8;
    gB[i] = wdt + wb + (size_t)(ntile * 128 + r) * F_DIM + kbase + q * 8;
    lA[i] = smA + c * 8;
    lB[i] = smB + c * 8;
  }

  f32x4 acc[4][4];
#pragma unroll
  for (int i = 0; i < 4; i++)
#pragma unroll
    for (int j = 0; j < 4; j++) acc[i][j] = (f32x4){0.f, 0.f, 0.f, 0.f};

  int m = lane & 15, quad = lane >> 4;
  for (int k0 = 0; k0 < F_DIM / 2; k0 += 32) {
#pragma unroll
    for (int i = 0; i < 2; i++) {
      async16(gA[i] + k0, lA[i]);
      async16(gB[i] + k0, lB[i]);
    }
    __syncthreads();
    bf16x8 a[4], b[4];
#pragma unroll
    for (int i = 0; i < 4; i++) {
      int rowa = wm * 64 + 16 * i + m;
      int rowb = wn * 64 + 16 * i + m;
      a[i] = *(const bf16x8*)(smA + rowa * 32 + ((quad ^ (rowa & 3)) * 8));
      b[i] = *(const bf16x8*)(smB + rowb * 32 + ((quad ^ (rowb & 3)) * 8));
    }
#pragma unroll
    for (int i = 0; i < 4; i++)
#pragma unroll
      for (int j = 0; j < 4; j++) acc[i][j] = mfma16(a[i], b[j], acc[i][j]);
    __syncthreads();
  }

  float* Yk = Y + (size_t)ks * ROWS_CAP * H_DIM;
#pragma unroll
  for (int i = 0; i < 4; i++)
#pragma unroll
    for (int r = 0; r < 4; r++) {
      int rt = wm * 64 + 16 * i + quad * 4 + r;
      int lrow = rowbase + rt;
      if (lrow < cnt) {
        float cw = roww[off + lrow];
#pragma unroll
        for (int j = 0; j < 4; j++) {
          int h = ntile * 128 + wn * 64 + 16 * j + m;
          Yk[(size_t)(off + lrow) * H_DIM + h] = cw * acc[i][j][r];
        }
      }
    }
}

// out[t] = sum over 2 rows x 2 k-slices of Y
__global__ __launch_bounds__(256) void combine_kernel(const float* __restrict__ Y,
                                                      const int* __restrict__ t2row,
                                                      float* __restrict__ out) {
  int t = blockIdx.x, hc = threadIdx.x;
  int r0 = t2row[2 * t], r1 = t2row[2 * t + 1];
  const float* Y1 = Y + (size_t)ROWS_CAP * H_DIM;
  float4 a = ((const float4*)(Y  + (size_t)r0 * H_DIM))[hc];
  float4 b = ((const float4*)(Y  + (size_t)r1 * H_DIM))[hc];
  float4 c = ((const float4*)(Y1 + (size_t)r0 * H_DIM))[hc];
  float4 d = ((const float4*)(Y1 + (size_t)r1 * H_DIM))[hc];
  float4 o;
  o.x = (a.x + b.x) + (c.x + d.x);
  o.y = (a.y + b.y) + (c.y + d.y);
  o.z = (a.z + b.z) + (c.z + d.z);
  o.w = (a.w + b.w) + (c.w + d.w);
  ((float4*)(out + (size_t)t * H_DIM))[hc] = o;
}

// ---------------- host ----------------

extern "C" void kernel_launch(void* const* d_in, const int* in_sizes, int n_in,
                              void* d_out, int out_size, void* d_ws, size_t ws_size,
                              hipStream_t stream) {
  const float* x  = (const float*)d_in[0];
  const float* rw = (const float*)d_in[1];
  const float* wg = (const float*)d_in[2];
  const float* wu = (const float*)d_in[3];
  const float* wd = (const float*)d_in[4];
  float* out = (float*)d_out;

  char* ws = (char*)d_ws;
  size_t p = 0;
  auto alloc = [&](size_t bytes) {
    char* r = ws + p;
    p = (p + bytes + 255) & ~(size_t)255;
    return r;
  };
  unsigned short* Xb  = (unsigned short*)alloc((size_t)T_TOK * H_DIM * 2);
  unsigned short* Wgt = (unsigned short*)alloc((size_t)E_NUM * F_DIM * H_DIM * 2);
  unsigned short* Wut = (unsigned short*)alloc((size_t)E_NUM * F_DIM * H_DIM * 2);
  unsigned short* Wdt = (unsigned short*)alloc((size_t)E_NUM * H_DIM * F_DIM * 2);
  unsigned short* Act = (unsigned short*)alloc((size_t)ROWS_CAP * F_DIM * 2);
  int*   t2i = (int*)alloc(T_TOK * 2 * 4);
  float* t2w = (float*)alloc(T_TOK * 2 * 4);
  int*   t2row = (int*)alloc(T_TOK * 2 * 4);
  int*   row2token = (int*)alloc(ROWS_CAP * 4);
  float* roww = (float*)alloc(ROWS_CAP * 4);
  int* ctrs = (int*)alloc(64 * 4);
  int* counts  = ctrs;        // 8
  int* cursors = ctrs + 8;    // 8
  float* psum  = (float*)(ctrs + 16);  // 8
  int* offsets = ctrs + 24;   // 9
  // Y (2 k-slices): 2*9216*1024*4 = 75.5 MB, overlays Wgt+Wut (92.3 MB, dead after gateup)
  float* Y = (float*)Wgt;

  hipMemsetAsync(ctrs, 0, 96, stream);

  conv_x_kernel<<<T_TOK * H_DIM / 4 / 256, 256, 0, stream>>>(x, Xb);
  transpose_all<<<dim3(2112, E_NUM), 256, 0, stream>>>(wg, wu, wd, Wgt, Wut, Wdt);

  router_kernel<<<T_TOK / 16, 256, 0, stream>>>(x, rw, t2i, t2w, counts, psum);
  scan_aux_kernel<<<1, 64, 0, stream>>>(counts, psum, offsets, cursors, out + (size_t)T_TOK * H_DIM);
  assign_kernel<<<T_TOK / 256, 256, 0, stream>>>(t2i, t2w, cursors, row2token, roww, t2row);

  gateup_kernel<<<dim3(TOTAL_MT, F_DIM / 64), 256, 0, stream>>>(Xb, Wgt, Wut, Act, counts, offsets, row2token);
  down_kernel<<<dim3(TOTAL_MT, H_DIM / 128, 2), 256, 0, stream>>>(Act, Wdt, counts, offsets, roww, Y);
  combine_kernel<<<T_TOK, 256, 0, stream>>>(Y, t2row, out);
}